// Round 6
// baseline (230.399 us; speedup 1.0000x reference)
//
#include <hip/hip_runtime.h>
#include <math.h>

#define NN   10000
#define DEG  16
#define SS   128
#define NRBF 20
#define GG   64
#define RC   10.0f
#define PI_F 3.14159265358979323846f
#define NB   8

__device__ __forceinline__ float silu_f(float x){
    return x / (1.0f + __expf(-x));
}

// ---------------------------------------------------------------------------
// Kernel 1a: h = silu(s0 @ phi_w1 + b1)  (s0 uniform). Also zeroes gs.
// ---------------------------------------------------------------------------
__global__ __launch_bounds__(256) void k_phi1(
    const float* __restrict__ emb0,
    const float* __restrict__ w1, const float* __restrict__ b1,
    float* __restrict__ phiH, float* __restrict__ gs){
    __shared__ float s0[SS];
    __shared__ float part[2][SS];
    int t = threadIdx.x;
    for (int i = t; i < GG*SS; i += 256) gs[i] = 0.0f;
    if (t < SS) s0[t] = 128.0f * emb0[t];
    __syncthreads();
    int c = t & 127, half = t >> 7;
    float acc = 0.0f;
    int s0i = half * 64;
    #pragma unroll 8
    for (int s = 0; s < 64; s++)
        acc = fmaf(s0[s0i + s], w1[(s0i + s)*SS + c], acc);
    part[half][c] = acc;
    __syncthreads();
    if (t < SS) phiH[t] = silu_f(b1[t] + part[0][t] + part[1][t]);
}

// ---------------------------------------------------------------------------
// Kernel 1b: phiW = h @ phi_w2 + b2.
// ---------------------------------------------------------------------------
__global__ __launch_bounds__(128) void k_phi2(
    const float* __restrict__ phiH,
    const float* __restrict__ w2, const float* __restrict__ b2,
    float* __restrict__ phiW){
    __shared__ float hL[SS];
    __shared__ float part[4][32];
    int t = threadIdx.x;
    hL[t] = phiH[t];
    __syncthreads();
    int c  = blockIdx.x*32 + (t & 31);
    int kk = t >> 5;
    float acc = 0.0f;
    int sbase = kk * 32;
    #pragma unroll 8
    for (int s = 0; s < 32; s++)
        acc = fmaf(hL[sbase + s], w2[(sbase + s)*3*SS + c], acc);
    part[kk][t & 31] = acc;
    __syncthreads();
    if (t < 32){
        int cc = blockIdx.x*32 + t;
        phiW[cc] = b2[cc] + part[0][t] + part[1][t] + part[2][t] + part[3][t];
    }
}

// ---------------------------------------------------------------------------
// Kernel 2: per-node edge processing (unchanged — round-0 proven).
// ---------------------------------------------------------------------------
__global__ __launch_bounds__(128) void k_edge(
    const float* __restrict__ evd, const float* __restrict__ elen,
    const int* __restrict__ node_from,
    const float* __restrict__ filt_w, const float* __restrict__ filt_b,
    const float* __restrict__ phiW,
    float* __restrict__ state, float* __restrict__ sv){
    __shared__ float rS[DEG];
    __shared__ float mcL[DEG];
    __shared__ float frL[DEG];
    __shared__ float eV[DEG][3];
    __shared__ float rbfL[DEG][NRBF];
    __shared__ float invD;
    int n = blockIdx.x;
    int t = threadIdx.x;

    if (t < DEG){
        int e = n*DEG + t;
        float x = evd[3*e+0], y = evd[3*e+1], z = evd[3*e+2];
        float r = sqrtf(x*x + y*y + z*z);
        float len  = elen[e];
        float mask = (fabsf(len) <= RC) ? 1.0f : 0.0f;
        float cut  = (r < RC) ? 0.5f*(cosf(PI_F*r*(1.0f/RC)) + 1.0f) : 0.0f;
        rS[t]  = fmaxf(r, 1e-12f);
        mcL[t] = mask * cut;
        frL[t] = mask * r * r;
        eV[t][0] = x; eV[t][1] = y; eV[t][2] = z;
    }
    __syncthreads();
    for (int idx = t; idx < DEG*NRBF; idx += 128){
        int e = idx / NRBF, k = idx % NRBF;
        float rs = rS[e];
        rbfL[e][k] = sinf((float)(k+1) * (PI_F/RC) * rs) / rs;
    }
    if (t == 0){
        float s = 0.0f;
        for (int e = 0; e < DEG; e++) s += frL[e];
        float fbn = sqrtf(s);
        invD = (fbn > 0.0f) ? 1.0f/fbn : 1.0f;
    }
    __syncthreads();

    int gc1 = SS + t;
    int gc2 = 2*SS + t;
    float fw1[NRBF], fw2[NRBF];
    #pragma unroll
    for (int k = 0; k < NRBF; k++){
        fw1[k] = filt_w[k*(3*SS) + gc1];
        fw2[k] = filt_w[k*(3*SS) + gc2];
    }
    float fb1 = filt_b[gc1], fb2 = filt_b[gc2];
    float ph1 = phiW[gc1],   ph2 = phiW[gc2];
    float iD  = invD;
    int   s3  = t % 3;

    float acc1 = 0.0f, acc2 = 0.0f;
    for (int e = 0; e < DEG; e++){
        float mc = mcL[e];
        if (mc == 0.0f) continue;
        const float4* rv = (const float4*)(&rbfL[e][0]);
        float4 r0 = rv[0], r1 = rv[1], r2 = rv[2], r3 = rv[3], r4 = rv[4];
        float rr[20] = {r0.x,r0.y,r0.z,r0.w, r1.x,r1.y,r1.z,r1.w,
                        r2.x,r2.y,r2.z,r2.w, r3.x,r3.y,r3.z,r3.w,
                        r4.x,r4.y,r4.z,r4.w};
        float w1 = fb1, w2 = fb2;
        #pragma unroll
        for (int k = 0; k < NRBF; k++){
            w1 = fmaf(rr[k], fw1[k], w1);
            w2 = fmaf(rr[k], fw2[k], w2);
        }
        acc1 = fmaf(ph1*mc, w1, acc1);
        acc2 = fmaf(ph2*mc*eV[e][s3]*iD, w2, acc2);
    }
    int nf = node_from[n*DEG];
    state[nf*SS + t] = acc1;
    sv[nf*SS + t]    = acc2;
}

// ---------------------------------------------------------------------------
// Kernel 3: per-node update, CHANNEL-VECTORIZED.
// Thread = (channel-quad cq = t&31 -> channels 4cq..4cq+3, node-pair pr = t>>5
// -> nodes 2pr, 2pr+1). NB=8 nodes/block, 1250 blocks.
// Weight loads are float4 (global_load_dwordx4, lane-contiguous 16B/lane):
// per loop1 iter, 2 loads feed 16 FMAs (2x round-4's FMA:load ratio, 4x fewer
// load instrs + addr calc). Diagnosis rounds 0-5: dur invariant to occupancy
// (14-46%) and L2 traffic (480-960MB); VALUBusy pinned ~30% by the
// 8-FMA-per-scalar-load dependency chain. Attack the chain, not the waves.
// ---------------------------------------------------------------------------
__global__ __launch_bounds__(128) void k_update(
    const float* __restrict__ state, const float* __restrict__ sv,
    const float* __restrict__ u_w, const float* __restrict__ v_w,
    const float* __restrict__ upd_w1, const float* __restrict__ upd_b1,
    const float* __restrict__ upd_w2, const float* __restrict__ upd_b2,
    const int* __restrict__ ngi, float* __restrict__ gs){
    __shared__ __align__(16) float svT[SS][NB];     // [s][node] 4KB
    __shared__ __align__(16) float xT[2*SS][NB];    // [i][node]: i<SS Vnorm, i>=SS state
    __shared__ __align__(16) float h2T[SS][NB];     // 4KB
    __shared__ float dL[NB];
    int t  = threadIdx.x;
    int cq = t & 31;          // channel quad: channels c0..c0+3
    int c0 = cq * 4;
    int pr = t >> 5;          // node pair: nodes 2pr, 2pr+1
    int n0 = blockIdx.x * NB;

    for (int idx = t; idx < NB*SS; idx += 128){
        int b = idx >> 7, s = idx & (SS-1);
        svT[s][b]   = sv[(n0+b)*SS + s];
        xT[SS+s][b] = state[(n0+b)*SS + s];
    }
    __syncthreads();

    // ---- loop1: U = sv@u_w, V = sv@v_w for 4 channels x 2 nodes
    float accU[2][4], accV[2][4];
    #pragma unroll
    for (int b = 0; b < 2; b++)
        #pragma unroll
        for (int j = 0; j < 4; j++){ accU[b][j]=0.f; accV[b][j]=0.f; }
    #pragma unroll 2
    for (int s = 0; s < SS; s++){
        float4 wu = *((const float4*)(u_w + s*SS + c0));
        float4 wv = *((const float4*)(v_w + s*SS + c0));
        float wua[4] = {wu.x,wu.y,wu.z,wu.w};
        float wva[4] = {wv.x,wv.y,wv.z,wv.w};
        float2 s2 = *((const float2*)(&svT[s][pr*2]));
        float sn[2] = {s2.x, s2.y};
        #pragma unroll
        for (int b = 0; b < 2; b++)
            #pragma unroll
            for (int j = 0; j < 4; j++){
                accU[b][j] = fmaf(sn[b], wua[j], accU[b][j]);
                accV[b][j] = fmaf(sn[b], wva[j], accV[b][j]);
            }
    }

    // dot product over channels: 4 serial + 32-lane tree (covers all 128 ch)
    float du[2];
    #pragma unroll
    for (int b = 0; b < 2; b++){
        du[b] = accU[b][0]*accV[b][0] + accU[b][1]*accV[b][1]
              + accU[b][2]*accV[b][2] + accU[b][3]*accV[b][3];
    }
    #pragma unroll
    for (int off = 16; off; off >>= 1){
        du[0] += __shfl_down(du[0], off, 32);
        du[1] += __shfl_down(du[1], off, 32);
    }
    if (cq == 0){ dL[pr*2] = du[0]; dL[pr*2+1] = du[1]; }

    // Vnorm = sqrt(3 v^2) into xT[0..SS)
    #pragma unroll
    for (int j = 0; j < 4; j++){
        xT[c0+j][pr*2+0] = sqrtf(3.f*accV[0][j]*accV[0][j]);
        xT[c0+j][pr*2+1] = sqrtf(3.f*accV[1][j]*accV[1][j]);
    }
    __syncthreads();

    // ---- loop2: h = silu(x @ upd_w1 + b1), x = [Vnorm, state] (2S inputs)
    float accH[2][4];
    #pragma unroll
    for (int b = 0; b < 2; b++)
        #pragma unroll
        for (int j = 0; j < 4; j++) accH[b][j] = 0.f;
    #pragma unroll 2
    for (int i = 0; i < 2*SS; i++){
        float4 w = *((const float4*)(upd_w1 + i*SS + c0));
        float wa[4] = {w.x,w.y,w.z,w.w};
        float2 x2 = *((const float2*)(&xT[i][pr*2]));
        float xv[2] = {x2.x, x2.y};
        #pragma unroll
        for (int b = 0; b < 2; b++)
            #pragma unroll
            for (int j = 0; j < 4; j++)
                accH[b][j] = fmaf(xv[b], wa[j], accH[b][j]);
    }
    {
        float4 b1q = *((const float4*)(upd_b1 + c0));
        float b1a[4] = {b1q.x,b1q.y,b1q.z,b1q.w};
        #pragma unroll
        for (int j = 0; j < 4; j++){
            h2T[c0+j][pr*2+0] = silu_f(accH[0][j] + b1a[j]);
            h2T[c0+j][pr*2+1] = silu_f(accH[1][j] + b1a[j]);
        }
    }
    __syncthreads();

    // ---- loop3: a_sv, a_ss channels of h @ upd_w2
    float a1[2][4], a2[2][4];
    #pragma unroll
    for (int b = 0; b < 2; b++)
        #pragma unroll
        for (int j = 0; j < 4; j++){ a1[b][j]=0.f; a2[b][j]=0.f; }
    #pragma unroll 2
    for (int s = 0; s < SS; s++){
        float4 wa4 = *((const float4*)(upd_w2 + s*3*SS + SS   + c0));
        float4 wb4 = *((const float4*)(upd_w2 + s*3*SS + 2*SS + c0));
        float waa[4] = {wa4.x,wa4.y,wa4.z,wa4.w};
        float wba[4] = {wb4.x,wb4.y,wb4.z,wb4.w};
        float2 h2 = *((const float2*)(&h2T[s][pr*2]));
        float hv[2] = {h2.x, h2.y};
        #pragma unroll
        for (int b = 0; b < 2; b++)
            #pragma unroll
            for (int j = 0; j < 4; j++){
                a1[b][j] = fmaf(hv[b], waa[j], a1[b][j]);
                a2[b][j] = fmaf(hv[b], wba[j], a2[b][j]);
            }
    }
    {
        float4 bsvq = *((const float4*)(upd_b2 + SS   + c0));
        float4 bssq = *((const float4*)(upd_b2 + 2*SS + c0));
        float bsva[4] = {bsvq.x,bsvq.y,bsvq.z,bsvq.w};
        float bssa[4] = {bssq.x,bssq.y,bssq.z,bssq.w};
        #pragma unroll
        for (int b = 0; b < 2; b++){
            int node = pr*2 + b;
            float d3 = 3.0f * dL[node];
            int g = ngi[n0 + node];
            #pragma unroll
            for (int j = 0; j < 4; j++){
                float ns = (a2[b][j] + bssa[j]) + d3*(a1[b][j] + bsva[j]);
                atomicAdd(&gs[g*SS + c0 + j], ns);
            }
        }
    }
}

// ---------------------------------------------------------------------------
// Kernel 4: readout per graph
// ---------------------------------------------------------------------------
__global__ __launch_bounds__(128) void k_out(
    const float* __restrict__ gs,
    const float* __restrict__ w1, const float* __restrict__ b1,
    const float* __restrict__ w2, const float* __restrict__ b2,
    float* __restrict__ out){
    __shared__ float gsL[SS];
    __shared__ float red[2];
    int g = blockIdx.x, t = threadIdx.x;
    gsL[t] = gs[g*SS + t];
    __syncthreads();
    float acc = b1[t];
    #pragma unroll 4
    for (int s = 0; s < SS; s++) acc = fmaf(gsL[s], w1[s*SS + t], acc);
    float p = silu_f(acc) * w2[t];
    for (int off = 32; off; off >>= 1) p += __shfl_down(p, off);
    if ((t & 63) == 0) red[t >> 6] = p;
    __syncthreads();
    if (t == 0) out[g] = red[0] + red[1] + b2[0];
}

extern "C" void kernel_launch(void* const* d_in, const int* in_sizes, int n_in,
                              void* d_out, int out_size, void* d_ws, size_t ws_size,
                              hipStream_t stream) {
    const float* evd     = (const float*)d_in[0];
    const float* elen    = (const float*)d_in[1];
    const int*   nfrom   = (const int*)  d_in[2];
    const int*   ngi     = (const int*)  d_in[3];
    // d_in[4] = num_graphs (device scalar) — G=64 fixed by setup
    const float* emb0    = (const float*)d_in[5];
    const float* phi_w1  = (const float*)d_in[6];
    const float* phi_b1  = (const float*)d_in[7];
    const float* phi_w2  = (const float*)d_in[8];
    const float* phi_b2  = (const float*)d_in[9];
    const float* filt_w  = (const float*)d_in[10];
    const float* filt_b  = (const float*)d_in[11];
    const float* u_w     = (const float*)d_in[12];
    const float* v_w     = (const float*)d_in[13];
    const float* upd_w1  = (const float*)d_in[14];
    const float* upd_b1  = (const float*)d_in[15];
    const float* upd_w2  = (const float*)d_in[16];
    const float* upd_b2  = (const float*)d_in[17];
    const float* out_w1  = (const float*)d_in[18];
    const float* out_b1  = (const float*)d_in[19];
    const float* out_w2  = (const float*)d_in[20];
    const float* out_b2  = (const float*)d_in[21];

    float* ws    = (float*)d_ws;
    float* phiW  = ws;                       // 384 (pad to 512)
    float* state = ws + 512;                 // N*S
    float* sv    = state + NN*SS;            // N*S
    float* gs    = sv + NN*SS;               // G*S
    float* phiH  = gs + GG*SS;               // 128

    k_phi1<<<1, 256, 0, stream>>>(emb0, phi_w1, phi_b1, phiH, gs);
    k_phi2<<<12, 128, 0, stream>>>(phiH, phi_w2, phi_b2, phiW);
    k_edge<<<NN, 128, 0, stream>>>(evd, elen, nfrom, filt_w, filt_b, phiW, state, sv);
    k_update<<<NN/NB, 128, 0, stream>>>(state, sv, u_w, v_w,
                                        upd_w1, upd_b1, upd_w2, upd_b2, ngi, gs);
    k_out<<<GG, 128, 0, stream>>>(gs, out_w1, out_b1, out_w2, out_b2, (float*)d_out);
}

// Round 7
// 171.729 us; speedup vs baseline: 1.3416x; 1.3416x over previous
//
#include <hip/hip_runtime.h>
#include <math.h>

#define NN   10000
#define DEG  16
#define SS   128
#define NRBF 20
#define GG   64
#define RC   10.0f
#define PI_F 3.14159265358979323846f
#define NB   4

__device__ __forceinline__ float silu_f(float x){
    return x / (1.0f + __expf(-x));
}

// ---------------------------------------------------------------------------
// Kernel 1: fused phi. 12 blocks x 128 threads. Each block redundantly
// computes phiH = silu(s0 @ phi_w1 + b1) (s0 uniform; 128 MAC/thread,
// w1 re-read 12x64KB = trivial L2 traffic), then its 32 phiW channels via
// the proven split-K phi2 loop. Also zeroes gs. Replaces two serial launches
// (k_phi1 was a single-block serializer on the critical path).
// ---------------------------------------------------------------------------
__global__ __launch_bounds__(128) void k_phi(
    const float* __restrict__ emb0,
    const float* __restrict__ w1, const float* __restrict__ b1,
    const float* __restrict__ w2, const float* __restrict__ b2,
    float* __restrict__ phiW, float* __restrict__ gs){
    __shared__ float s0[SS];
    __shared__ float hL[SS];
    __shared__ float part[4][32];
    int t = threadIdx.x, bid = blockIdx.x;
    for (int i = bid*128 + t; i < GG*SS; i += 12*128) gs[i] = 0.0f;
    s0[t] = 128.0f * emb0[t];
    __syncthreads();
    float acc = 0.0f;
    #pragma unroll 8
    for (int s = 0; s < SS; s++)
        acc = fmaf(s0[s], w1[s*SS + t], acc);
    hL[t] = silu_f(acc + b1[t]);
    __syncthreads();
    int c  = bid*32 + (t & 31);
    int kk = t >> 5;
    float a2 = 0.0f;
    int sbase = kk * 32;
    #pragma unroll 8
    for (int s = 0; s < 32; s++)
        a2 = fmaf(hL[sbase + s], w2[(sbase + s)*3*SS + c], a2);
    part[kk][t & 31] = a2;
    __syncthreads();
    if (t < 32){
        int cc = bid*32 + t;
        phiW[cc] = b2[cc] + part[0][t] + part[1][t] + part[2][t] + part[3][t];
    }
}

// ---------------------------------------------------------------------------
// Kernel 2: FUSED edge + update. NB=4 nodes per 128-thread block, 2500 blocks.
// Phase A (edge, ex-k_edge): per node, accumulate m2/m3 messages over its 16
// contiguous edges, writing results DIRECTLY into the LDS buffers the update
// phase consumes (svT/xT). Eliminates the 20MB state/sv HBM round-trip and a
// kernel launch. Phase B (update) is the round-4 proven code verbatim
// (thread=channel, coalesced scalar weight loads, float4 LDS broadcasts --
// the fastest of the 5 weight-delivery schemes measured in rounds 0-6).
// ---------------------------------------------------------------------------
__global__ __launch_bounds__(128) void k_node(
    const float* __restrict__ evd, const float* __restrict__ elen,
    const float* __restrict__ filt_w, const float* __restrict__ filt_b,
    const float* __restrict__ phiW,
    const float* __restrict__ u_w, const float* __restrict__ v_w,
    const float* __restrict__ upd_w1, const float* __restrict__ upd_b1,
    const float* __restrict__ upd_w2, const float* __restrict__ upd_b2,
    const int* __restrict__ ngi, float* __restrict__ gs){
    __shared__ float rS[NB*DEG];
    __shared__ float mcL[NB*DEG];
    __shared__ float frL[NB*DEG];
    __shared__ float eV[NB*DEG][3];
    __shared__ float rbfL[NB*DEG][NRBF];
    __shared__ float invD[NB];
    __shared__ __align__(16) float svT[SS][NB];     // [s][node] : sv (m3 path)
    __shared__ __align__(16) float xT[2*SS][NB];    // i<SS Vnorm, i>=SS state (m2 path)
    __shared__ __align__(16) float h2T[SS][NB];
    __shared__ float red[2][NB];
    __shared__ float dL[NB];
    int t  = threadIdx.x;
    int n0 = blockIdx.x * NB;

    // ---------------- Phase A: edge processing for NB nodes ----------------
    if (t < NB*DEG){
        int e = n0*DEG + t;
        float x = evd[3*e+0], y = evd[3*e+1], z = evd[3*e+2];
        float r = sqrtf(x*x + y*y + z*z);
        float len  = elen[e];
        float mask = (fabsf(len) <= RC) ? 1.0f : 0.0f;
        float cut  = (r < RC) ? 0.5f*(cosf(PI_F*r*(1.0f/RC)) + 1.0f) : 0.0f;
        rS[t]  = fmaxf(r, 1e-12f);
        mcL[t] = mask * cut;
        frL[t] = mask * r * r;
        eV[t][0] = x; eV[t][1] = y; eV[t][2] = z;
    }
    __syncthreads();
    for (int idx = t; idx < NB*DEG*NRBF; idx += 128){
        int e = idx / NRBF, k = idx % NRBF;
        float rs = rS[e];
        rbfL[e][k] = sinf((float)(k+1) * (PI_F/RC) * rs) / rs;
    }
    if (t < NB){
        float s = 0.0f;
        for (int j = 0; j < DEG; j++) s += frL[t*DEG + j];
        float fbn = sqrtf(s);
        invD[t] = (fbn > 0.0f) ? 1.0f/fbn : 1.0f;
    }
    __syncthreads();

    {
        int gc1 = SS + t;      // m2 channel (-> state)
        int gc2 = 2*SS + t;    // m3 channel (-> sv)
        float fw1[NRBF], fw2[NRBF];
        #pragma unroll
        for (int k = 0; k < NRBF; k++){
            fw1[k] = filt_w[k*(3*SS) + gc1];
            fw2[k] = filt_w[k*(3*SS) + gc2];
        }
        float fb1 = filt_b[gc1], fb2 = filt_b[gc2];
        float ph1 = phiW[gc1],   ph2 = phiW[gc2];
        int   s3  = t % 3;

        for (int b = 0; b < NB; b++){
            float iD = invD[b];
            float acc1 = 0.0f, acc2 = 0.0f;
            for (int e = 0; e < DEG; e++){
                int ee = b*DEG + e;
                float mc = mcL[ee];
                if (mc == 0.0f) continue;   // wave-uniform skip
                const float4* rv = (const float4*)(&rbfL[ee][0]);
                float4 r0 = rv[0], r1 = rv[1], r2 = rv[2], r3 = rv[3], r4 = rv[4];
                float rr[20] = {r0.x,r0.y,r0.z,r0.w, r1.x,r1.y,r1.z,r1.w,
                                r2.x,r2.y,r2.z,r2.w, r3.x,r3.y,r3.z,r3.w,
                                r4.x,r4.y,r4.z,r4.w};
                float w1v = fb1, w2v = fb2;
                #pragma unroll
                for (int k = 0; k < NRBF; k++){
                    w1v = fmaf(rr[k], fw1[k], w1v);
                    w2v = fmaf(rr[k], fw2[k], w2v);
                }
                acc1 = fmaf(ph1*mc, w1v, acc1);
                acc2 = fmaf(ph2*mc*eV[ee][s3]*iD, w2v, acc2);
            }
            svT[t][b]   = acc2;   // sv
            xT[SS+t][b] = acc1;   // state
        }
    }
    __syncthreads();

    // ---------------- Phase B: update (round-4 proven code) ----------------
    // ---- loop1: U = sv@u_w, V = sv@v_w for channel t, NB nodes
    float accU[NB], accV[NB];
    #pragma unroll
    for (int b = 0; b < NB; b++){ accU[b]=0.f; accV[b]=0.f; }
    for (int s = 0; s < SS; s++){
        float wu = u_w[s*SS + t];
        float wv = v_w[s*SS + t];
        float4 s03 = *((const float4*)(&svT[s][0]));
        float svv[NB] = {s03.x,s03.y,s03.z,s03.w};
        #pragma unroll
        for (int b = 0; b < NB; b++){
            accU[b] = fmaf(svv[b], wu, accU[b]);
            accV[b] = fmaf(svv[b], wv, accV[b]);
        }
    }

    int lane = t & 63, wid = t >> 6;
    #pragma unroll
    for (int b = 0; b < NB; b++){
        float p = accU[b]*accV[b];
        for (int off = 32; off; off >>= 1) p += __shfl_down(p, off);
        if (lane == 0) red[wid][b] = p;
    }
    {   // Vnorm = sqrt(V0^2+V1^2+V2^2) with V0=V1=V2 -> sqrt(3 v^2)
        float4 q0;
        q0.x = sqrtf(3.f*accV[0]*accV[0]); q0.y = sqrtf(3.f*accV[1]*accV[1]);
        q0.z = sqrtf(3.f*accV[2]*accV[2]); q0.w = sqrtf(3.f*accV[3]*accV[3]);
        ((float4*)(&xT[t][0]))[0] = q0;
    }
    __syncthreads();
    if (t < NB) dL[t] = red[0][t] + red[1][t];

    // ---- loop2: h = silu(x @ upd_w1 + b1), x = [Vnorm, state] (2S inputs)
    float accH[NB];
    #pragma unroll
    for (int b = 0; b < NB; b++) accH[b] = 0.f;
    for (int i = 0; i < 2*SS; i++){
        float w = upd_w1[i*SS + t];
        float4 x03 = *((const float4*)(&xT[i][0]));
        float xv[NB] = {x03.x,x03.y,x03.z,x03.w};
        #pragma unroll
        for (int b = 0; b < NB; b++) accH[b] = fmaf(xv[b], w, accH[b]);
    }
    float b1v = upd_b1[t];
    {
        float4 q0;
        q0.x = silu_f(accH[0]+b1v); q0.y = silu_f(accH[1]+b1v);
        q0.z = silu_f(accH[2]+b1v); q0.w = silu_f(accH[3]+b1v);
        ((float4*)(&h2T[t][0]))[0] = q0;
    }
    __syncthreads();

    // ---- loop3: a_sv, a_ss channels of h @ upd_w2
    float a1[NB], a2[NB];
    #pragma unroll
    for (int b = 0; b < NB; b++){ a1[b]=0.f; a2[b]=0.f; }
    for (int j = 0; j < SS; j++){
        float w1 = upd_w2[j*3*SS + SS   + t];   // a_sv channel
        float w2 = upd_w2[j*3*SS + 2*SS + t];   // a_ss channel
        float4 h03 = *((const float4*)(&h2T[j][0]));
        float hv[NB] = {h03.x,h03.y,h03.z,h03.w};
        #pragma unroll
        for (int b = 0; b < NB; b++){
            a1[b] = fmaf(hv[b], w1, a1[b]);
            a2[b] = fmaf(hv[b], w2, a2[b]);
        }
    }
    float bsv = upd_b2[SS+t], bss = upd_b2[2*SS+t];
    #pragma unroll
    for (int b = 0; b < NB; b++){
        float ns = (a2[b] + bss) + 3.0f*dL[b]*(a1[b] + bsv);
        int g = ngi[n0+b];
        atomicAdd(&gs[g*SS + t], ns);
    }
}

// ---------------------------------------------------------------------------
// Kernel 3: readout per graph
// ---------------------------------------------------------------------------
__global__ __launch_bounds__(128) void k_out(
    const float* __restrict__ gs,
    const float* __restrict__ w1, const float* __restrict__ b1,
    const float* __restrict__ w2, const float* __restrict__ b2,
    float* __restrict__ out){
    __shared__ float gsL[SS];
    __shared__ float red[2];
    int g = blockIdx.x, t = threadIdx.x;
    gsL[t] = gs[g*SS + t];
    __syncthreads();
    float acc = b1[t];
    #pragma unroll 4
    for (int s = 0; s < SS; s++) acc = fmaf(gsL[s], w1[s*SS + t], acc);
    float p = silu_f(acc) * w2[t];
    for (int off = 32; off; off >>= 1) p += __shfl_down(p, off);
    if ((t & 63) == 0) red[t >> 6] = p;
    __syncthreads();
    if (t == 0) out[g] = red[0] + red[1] + b2[0];
}

extern "C" void kernel_launch(void* const* d_in, const int* in_sizes, int n_in,
                              void* d_out, int out_size, void* d_ws, size_t ws_size,
                              hipStream_t stream) {
    const float* evd     = (const float*)d_in[0];
    const float* elen    = (const float*)d_in[1];
    // d_in[2] = node_from: edges of node n are [16n,16n+16) with from==n
    const int*   ngi     = (const int*)  d_in[3];
    // d_in[4] = num_graphs (device scalar) — G=64 fixed by setup
    const float* emb0    = (const float*)d_in[5];
    const float* phi_w1  = (const float*)d_in[6];
    const float* phi_b1  = (const float*)d_in[7];
    const float* phi_w2  = (const float*)d_in[8];
    const float* phi_b2  = (const float*)d_in[9];
    const float* filt_w  = (const float*)d_in[10];
    const float* filt_b  = (const float*)d_in[11];
    const float* u_w     = (const float*)d_in[12];
    const float* v_w     = (const float*)d_in[13];
    const float* upd_w1  = (const float*)d_in[14];
    const float* upd_b1  = (const float*)d_in[15];
    const float* upd_w2  = (const float*)d_in[16];
    const float* upd_b2  = (const float*)d_in[17];
    const float* out_w1  = (const float*)d_in[18];
    const float* out_b1  = (const float*)d_in[19];
    const float* out_w2  = (const float*)d_in[20];
    const float* out_b2  = (const float*)d_in[21];

    float* ws    = (float*)d_ws;
    float* phiW  = ws;                       // 384 (pad to 512)
    float* gs    = ws + 512;                 // G*S

    k_phi<<<12, 128, 0, stream>>>(emb0, phi_w1, phi_b1, phi_w2, phi_b2, phiW, gs);
    k_node<<<NN/NB, 128, 0, stream>>>(evd, elen, filt_w, filt_b, phiW,
                                      u_w, v_w, upd_w1, upd_b1, upd_w2, upd_b2,
                                      ngi, gs);
    k_out<<<GG, 128, 0, stream>>>(gs, out_w1, out_b1, out_w2, out_b2, (float*)d_out);
}